// Round 12
// baseline (339.937 us; speedup 1.0000x reference)
//
#include <hip/hip_runtime.h>
#include <stdint.h>

typedef unsigned short u16;
using s16x8 = __attribute__((ext_vector_type(8))) short;
using f32x4 = __attribute__((ext_vector_type(4))) float;
using u16x8 = __attribute__((ext_vector_type(8))) unsigned short;
using u16x4 = __attribute__((ext_vector_type(4))) unsigned short;

#define DEVINL __device__ __forceinline__

DEVINL float b2f(u16 u) { return __uint_as_float(((uint32_t)u) << 16); }
DEVINL u16 f2b(float f) {
  uint32_t x = __float_as_uint(f);
  return (u16)((x + 0x7fffu + ((x >> 16) & 1u)) >> 16);
}
DEVINL float ldf(const void* p, size_t i, int isbf) {
  return isbf ? b2f(((const u16*)p)[i]) : ((const float*)p)[i];
}
DEVINL void stf(void* p, size_t i, int isbf, float v) {
  if (isbf) ((u16*)p)[i] = f2b(v);
  else      ((float*)p)[i] = v;
}

typedef __attribute__((address_space(1))) const void gvoid;
typedef __attribute__((address_space(3))) void lvoid;
DEVINL void gload_lds16(const u16* g, u16* l) {
  __builtin_amdgcn_global_load_lds((gvoid*)g, (lvoid*)l, 16, 0, 0);
}

constexpr int NN = 10000;     // nodes
constexpr int NE = 80000;     // edges (no self loops)
constexpr int NTOT = 90000;   // edges + self loops

// ---------------------------------------------------------------- cvt (+ inline dtype detect)
// Wave 0 of each block samples x's u16 words: bf16 data has sane exponents.
__global__ void cvt_kernel(const void* __restrict__ in, u16* __restrict__ out,
                           int n, int* __restrict__ flagout) {
  __shared__ int sflag;
  if (threadIdx.x < 64) {
    u16 w = ((const u16*)in)[threadIdx.x * 97 + 13];
    int e = (w >> 7) & 0xFF;
    int sane = (e >= 0x50 && e <= 0x8A) ? 1 : 0;
    unsigned long long b = __ballot(sane);
    if (threadIdx.x == 0) sflag = (__popcll(b) >= 56) ? 1 : 0;
  }
  __syncthreads();
  int isbf = sflag;
  int i = blockIdx.x * 256 + threadIdx.x;
  if (i < n) out[i] = isbf ? ((const u16*)in)[i] : f2b(((const float*)in)[i]);
  if (blockIdx.x == 0 && threadIdx.x == 0) flagout[0] = isbf;
}

// ---------------------------------------------------------------- batched transpose
struct TD { const void* in; u16* out; int R, C, t0; };
struct TD5 { TD d[5]; };
__global__ void transpose_all(TD5 td, const int* __restrict__ FLAG) {
  int isbf = *FLAG;
  __shared__ float tile[32][33];
  int t = blockIdx.x;
  int k = 0;
#pragma unroll
  for (int j = 1; j < 5; j++) if (t >= td.d[j].t0) k = j;
  const void* in = td.d[k].in;
  u16* out = td.d[k].out;
  int R = td.d[k].R, C = td.d[k].C;
  int tl = t - td.d[k].t0;
  int tcols = C / 32;
  int bx = (tl % tcols) * 32, by = (tl / tcols) * 32;
  int tx = threadIdx.x, ty = threadIdx.y;  // (32,8)
  for (int j = 0; j < 32; j += 8) {
    int r = by + ty + j, c = bx + tx;
    tile[ty + j][tx] = ldf(in, (size_t)r * C + c, isbf);
  }
  __syncthreads();
  for (int j = 0; j < 32; j += 8) {
    int r = bx + ty + j, c = by + tx;
    out[(size_t)r * R + c] = f2b(tile[tx][ty + j]);
  }
}

// ---------------------------------------------------------------- CSR build + zero HS/HD
__global__ void init_kernel(int* __restrict__ deg, float* __restrict__ hz, int nz) {
  int i = blockIdx.x * blockDim.x + threadIdx.x;
  if (i < NN) deg[i] = 1;  // self loop
  if (i < nz) hz[i] = 0.f;
}

__global__ void count_deg_kernel(const int* __restrict__ ei, int* __restrict__ deg) {
  int e = blockIdx.x * blockDim.x + threadIdx.x;
  if (e < NE) atomicAdd(&deg[ei[NE + e]], 1);
}

__global__ __launch_bounds__(1024) void scan_kernel(const int* __restrict__ deg,
                                                    int* __restrict__ offs,
                                                    int* __restrict__ cursor, int n) {
  __shared__ int wsum[16];
  __shared__ int carry_s;
  int tid = threadIdx.x, lane = tid & 63, wid = tid >> 6;
  if (tid == 0) carry_s = 0;
  __syncthreads();
  for (int base = 0; base < n; base += 1024) {
    int idx = base + tid;
    int v = (idx < n) ? deg[idx] : 0;
    int s = v;
#pragma unroll
    for (int o = 1; o < 64; o <<= 1) { int t = __shfl_up(s, o); if (lane >= o) s += t; }
    if (lane == 63) wsum[wid] = s;
    __syncthreads();
    if (wid == 0) {
      int w = (lane < 16) ? wsum[lane] : 0;
#pragma unroll
      for (int o = 1; o < 16; o <<= 1) { int t = __shfl_up(w, o); if (lane >= o) w += t; }
      if (lane < 16) wsum[lane] = w;
    }
    __syncthreads();
    int inc = s + (wid > 0 ? wsum[wid - 1] : 0) + carry_s;
    if (idx < n) { offs[idx + 1] = inc; cursor[idx] = inc - v; }
    __syncthreads();
    if (tid == 0) carry_s += wsum[15];
    __syncthreads();
  }
  if (tid == 0) offs[0] = 0;
}

__global__ void scatter_kernel(const int* __restrict__ ei, int* __restrict__ cursor,
                               int* __restrict__ csr_src) {
  int e = blockIdx.x * blockDim.x + threadIdx.x;
  if (e >= NTOT) return;
  int s, d;
  if (e < NE) { s = ei[e]; d = ei[NE + e]; }
  else        { s = e - NE; d = s; }
  int pos = atomicAdd(&cursor[d], 1);
  csr_src[pos] = s;
}

// ---------------------------------------------------------------- GEMM (bf16 MFMA)
template <int BM, int BN, int WM, int WN>
__global__ __launch_bounds__(256) void gemm_kernel(const u16* __restrict__ A,
                                                   const u16* __restrict__ Bt,
                                                   u16* __restrict__ C,
                                                   int M, int K, int N, int nN,
                                                   const void* __restrict__ bias,
                                                   int do_relu,
                                                   const void* __restrict__ asrc,
                                                   const void* __restrict__ adst,
                                                   float* __restrict__ hs,
                                                   float* __restrict__ hd,
                                                   int H, int Cc,
                                                   const int* __restrict__ FLAG) {
  constexpr int BK = 64;             // 128 B per LDS row
  constexpr int WTM = BM / WM, WTN = BN / WN;
  constexpr int FM = WTM / 16, FN = WTN / 16;
  constexpr int ACH = BM / 32;
  constexpr int BCH = BN / 32;

  __shared__ u16 smem[(BM + BN) * BK];
  u16* lA = smem;
  u16* lB = smem + BM * BK;

  int tid = threadIdx.x;
  int lane = tid & 63, wid = tid >> 6;
  int wm = wid / WN, wn = wid % WN;
  int isbf = (bias || asrc) ? *FLAG : 0;

  // bijective XCD remap (m204)
  int nwg = gridDim.x;
  int q = nwg >> 3, r = nwg & 7;
  int xcd = blockIdx.x & 7, pos = blockIdx.x >> 3;
  int wgid = (xcd < r ? xcd * (q + 1) : r * (q + 1) + (xcd - r) * q) + pos;
  int bm0 = (wgid / nN) * BM, bn0 = (wgid % nN) * BN;

  int srow = lane >> 3;
  int scol = ((lane & 7) ^ (lane >> 3)) << 3;         // SWIZZLED source col (u16)

  f32x4 acc[FM][FN];
#pragma unroll
  for (int m = 0; m < FM; m++)
#pragma unroll
    for (int n = 0; n < FN; n++) acc[m][n] = (f32x4){0.f, 0.f, 0.f, 0.f};

  for (int k0 = 0; k0 < K; k0 += BK) {
#pragma unroll
    for (int i = 0; i < ACH; i++) {
      int c = wid * ACH + i;
      int row = c * 8 + srow;
      int grow = bm0 + row;
      if (grow > M - 1) grow = M - 1;
      gload_lds16(A + (size_t)grow * K + k0 + scol, lA + c * 512);
    }
#pragma unroll
    for (int i = 0; i < BCH; i++) {
      int c = wid * BCH + i;
      int row = c * 8 + srow;
      gload_lds16(Bt + (size_t)(bn0 + row) * K + k0 + scol, lB + c * 512);
    }
    __syncthreads();

    int swz = (lane & 7) << 4;
#pragma unroll
    for (int ks = 0; ks < 2; ks++) {
      int kb = ks * 64 + ((lane >> 4) << 4);
      s16x8 af[FM], bf[FN];
#pragma unroll
      for (int m = 0; m < FM; m++) {
        int row = wm * WTM + m * 16 + (lane & 15);
        af[m] = *(const s16x8*)((const char*)lA + row * 128 + (kb ^ swz));
      }
#pragma unroll
      for (int n = 0; n < FN; n++) {
        int row = wn * WTN + n * 16 + (lane & 15);
        bf[n] = *(const s16x8*)((const char*)lB + row * 128 + (kb ^ swz));
      }
#pragma unroll
      for (int m = 0; m < FM; m++)
#pragma unroll
        for (int n = 0; n < FN; n++)
          acc[m][n] = __builtin_amdgcn_mfma_f32_16x16x32_bf16(af[m], bf[n], acc[m][n], 0, 0, 0);
    }
    __syncthreads();
  }

  // ---- epilogue
  u16* lC = smem;
  int r0 = (lane >> 4) * 4;
  int head = hs ? (bn0 / Cc) : 0;
  int part = hs ? ((bn0 % Cc) / WTN + wn) : 0;   // wave-unique column slice
  float asv[FN], adv[FN];
  float sa[FM][4], da[FM][4];
  if (hs) {
#pragma unroll
    for (int n = 0; n < FN; n++) {
      int colC = (bn0 % Cc) + wn * WTN + n * 16 + (lane & 15);
      asv[n] = ldf(asrc, (size_t)head * Cc + colC, isbf);
      adv[n] = ldf(adst, (size_t)head * Cc + colC, isbf);
    }
#pragma unroll
    for (int m = 0; m < FM; m++)
#pragma unroll
      for (int rr = 0; rr < 4; rr++) { sa[m][rr] = 0.f; da[m][rr] = 0.f; }
  }
#pragma unroll
  for (int m = 0; m < FM; m++)
#pragma unroll
    for (int n = 0; n < FN; n++)
#pragma unroll
      for (int rr = 0; rr < 4; rr++) {
        int row = wm * WTM + m * 16 + r0 + rr;
        int col = wn * WTN + n * 16 + (lane & 15);
        float v = acc[m][n][rr];
        if (bias) v += ldf(bias, bn0 + col, isbf);
        if (do_relu) v = fmaxf(v, 0.f);
        if (hs) { sa[m][rr] += v * asv[n]; da[m][rr] += v * adv[n]; }
        lC[row * BN + col] = f2b(v);
      }
  if (hs) {
#pragma unroll
    for (int m = 0; m < FM; m++) {
#pragma unroll
      for (int mask = 1; mask < 16; mask <<= 1)
#pragma unroll
        for (int rr = 0; rr < 4; rr++) {
          sa[m][rr] += __shfl_xor(sa[m][rr], mask);
          da[m][rr] += __shfl_xor(da[m][rr], mask);
        }
      if ((lane & 15) == 0) {
#pragma unroll
        for (int rr = 0; rr < 4; rr++) {
          int grow = bm0 + wm * WTM + m * 16 + r0 + rr;
          if (grow < M) {
            hs[((size_t)grow * H + head) * 4 + part] = sa[m][rr];
            hd[((size_t)grow * H + head) * 4 + part] = da[m][rr];
          }
        }
      }
    }
  }
  if (C) {
    __syncthreads();
    constexpr int CHUNKS = BM * BN / 2048;
    constexpr int CPR = BN / 8;
#pragma unroll
    for (int j = 0; j < CHUNKS; j++) {
      int idx = j * 256 + tid;
      int row = idx / CPR, colb = (idx % CPR) * 16;
      int grow = bm0 + row;
      if (grow < M) {
        int4 v = *(const int4*)((const char*)lC + idx * 16);
        *(int4*)((char*)C + ((size_t)grow * N + bn0) * 2 + colb) = v;
      }
    }
  }
}

// ---------------------------------------------------------------- fused softmax + aggregation
// One block per dst node. TPB = H*L crew threads (L lanes per head).
// Fast path (deg<=ECAP): single global hs4 gather, LDS-cached e with PADDED
// stride (H+1) -> conflict-free; max/denom/normalize passes LDS-only.
// Fallback (deg>ECAP): chunked 3-global-pass path.
template <int HC, int VPT, int TPB, int H, int ECAP>
__global__ __launch_bounds__(TPB) void agg_fused_kernel(
    const u16* __restrict__ h, const float* __restrict__ hs, const float* __restrict__ hd,
    const int* __restrict__ csr_src, const int* __restrict__ offs,
    const void* __restrict__ bias, u16* __restrict__ outb, void* __restrict__ outv,
    int do_elu, const int* __restrict__ FLAG) {
  constexpr int C = HC / H;
  constexpr int L = (TPB / H) < 64 ? (TPB / H) : 64;  // crew lanes per head
  constexpr int PH = H + 1;                            // padded LDS stride
  constexpr int CH = 64;                               // fallback edge chunk
  int isbf = *FLAG;
  int i = blockIdx.x;
  int t = threadIdx.x;
  int p0 = offs[i], p1 = offs[i + 1];
  int deg = p1 - p0;
  __shared__ float m_s[H], inv_s[H], hd_s[H];
  __shared__ float lalpha[ECAP * PH];
  __shared__ int lsrc[ECAP];
  const float4* hs4 = (const float4*)hs;

  if (t < H) {
    float4 qd = ((const float4*)hd)[(size_t)i * H + t];
    hd_s[t] = (qd.x + qd.y) + (qd.z + qd.w);
  }
  __syncthreads();

  int hh = (t / L) % H, j = t % L;
  bool crew = (t < H * L);
  int c0 = t * VPT;
  int head = c0 / C;
  float acc[VPT];
#pragma unroll
  for (int v = 0; v < VPT; v++) acc[v] = 0.f;

  if (deg <= ECAP) {
    // ---------------- fast path: single global gather
    for (int idx = t; idx < deg; idx += TPB) lsrc[idx] = csr_src[p0 + idx];
    if (crew) {
      float hdv = hd_s[hh];
      float mm = -1e30f;
      for (int idx = j; idx < deg; idx += L) {
        float4 qv = hs4[(size_t)csr_src[p0 + idx] * H + hh];
        float e = (qv.x + qv.y) + (qv.z + qv.w) + hdv;
        e = e > 0.f ? e : 0.2f * e;
        lalpha[idx * PH + hh] = e;
        mm = fmaxf(mm, e);
      }
#pragma unroll
      for (int msk = L / 2; msk; msk >>= 1) mm = fmaxf(mm, __shfl_xor(mm, msk));
      float dd = 0.f;
      for (int idx = j; idx < deg; idx += L) {
        float v = __expf(lalpha[idx * PH + hh] - mm);
        lalpha[idx * PH + hh] = v;
        dd += v;
      }
#pragma unroll
      for (int msk = L / 2; msk; msk >>= 1) dd += __shfl_xor(dd, msk);
      float inv = 1.f / (dd + 1e-16f);
      for (int idx = j; idx < deg; idx += L)
        lalpha[idx * PH + hh] *= inv;
    }
    __syncthreads();

    int p = 0;
    if constexpr (VPT == 16) {
      for (; p + 2 <= deg; p += 2) {
        int s0 = lsrc[p], s1 = lsrc[p + 1];
        float a0 = lalpha[p * PH + head];
        float a1 = lalpha[(p + 1) * PH + head];
        const u16* h0 = h + (size_t)s0 * HC + c0;
        const u16* h1 = h + (size_t)s1 * HC + c0;
        u16x8 va0 = *(const u16x8*)h0, vb0 = *(const u16x8*)(h0 + 8);
        u16x8 va1 = *(const u16x8*)h1, vb1 = *(const u16x8*)(h1 + 8);
#pragma unroll
        for (int v = 0; v < 8; v++) {
          acc[v] += a0 * b2f(va0[v]) + a1 * b2f(va1[v]);
          acc[8 + v] += a0 * b2f(vb0[v]) + a1 * b2f(vb1[v]);
        }
      }
      for (; p < deg; ++p) {
        int s0 = lsrc[p];
        float a0 = lalpha[p * PH + head];
        const u16* h0 = h + (size_t)s0 * HC + c0;
        u16x8 va0 = *(const u16x8*)h0, vb0 = *(const u16x8*)(h0 + 8);
#pragma unroll
        for (int v = 0; v < 8; v++) {
          acc[v] += a0 * b2f(va0[v]);
          acc[8 + v] += a0 * b2f(vb0[v]);
        }
      }
    } else {
      for (; p + 4 <= deg; p += 4) {
        int s0 = lsrc[p], s1 = lsrc[p + 1], s2 = lsrc[p + 2], s3 = lsrc[p + 3];
        float a0 = lalpha[p * PH + head];
        float a1 = lalpha[(p + 1) * PH + head];
        float a2 = lalpha[(p + 2) * PH + head];
        float a3 = lalpha[(p + 3) * PH + head];
        const u16* h0 = h + (size_t)s0 * HC + c0;
        const u16* h1 = h + (size_t)s1 * HC + c0;
        const u16* h2 = h + (size_t)s2 * HC + c0;
        const u16* h3 = h + (size_t)s3 * HC + c0;
        if constexpr (VPT == 8) {
          u16x8 v0 = *(const u16x8*)h0, v1 = *(const u16x8*)h1;
          u16x8 v2 = *(const u16x8*)h2, v3 = *(const u16x8*)h3;
#pragma unroll
          for (int v = 0; v < 8; v++)
            acc[v] += (a0 * b2f(v0[v]) + a1 * b2f(v1[v])) + (a2 * b2f(v2[v]) + a3 * b2f(v3[v]));
        } else if constexpr (VPT == 4) {
          u16x4 v0 = *(const u16x4*)h0, v1 = *(const u16x4*)h1;
          u16x4 v2 = *(const u16x4*)h2, v3 = *(const u16x4*)h3;
#pragma unroll
          for (int v = 0; v < 4; v++)
            acc[v] += (a0 * b2f(v0[v]) + a1 * b2f(v1[v])) + (a2 * b2f(v2[v]) + a3 * b2f(v3[v]));
        } else {
          acc[0] += (a0 * b2f(h0[0]) + a1 * b2f(h1[0])) + (a2 * b2f(h2[0]) + a3 * b2f(h3[0]));
        }
      }
      for (; p < deg; ++p) {
        int s0 = lsrc[p];
        float a0 = lalpha[p * PH + head];
        const u16* h0 = h + (size_t)s0 * HC + c0;
        if constexpr (VPT == 8) {
          u16x8 v0 = *(const u16x8*)h0;
#pragma unroll
          for (int v = 0; v < 8; v++) acc[v] += a0 * b2f(v0[v]);
        } else if constexpr (VPT == 4) {
          u16x4 v0 = *(const u16x4*)h0;
#pragma unroll
          for (int v = 0; v < 4; v++) acc[v] += a0 * b2f(v0[v]);
        } else {
          acc[0] += a0 * b2f(h0[0]);
        }
      }
    }
  } else {
    // ---------------- fallback: chunked, 3 global passes
    if (crew) {
      float hdv = hd_s[hh];
      float mm = -1e30f;
      for (int p = p0 + j; p < p1; p += L) {
        float4 qv = hs4[(size_t)csr_src[p] * H + hh];
        float e = (qv.x + qv.y) + (qv.z + qv.w) + hdv;
        e = e > 0.f ? e : 0.2f * e;
        mm = fmaxf(mm, e);
      }
#pragma unroll
      for (int msk = L / 2; msk; msk >>= 1) mm = fmaxf(mm, __shfl_xor(mm, msk));
      float dd = 0.f;
      for (int p = p0 + j; p < p1; p += L) {
        float4 qv = hs4[(size_t)csr_src[p] * H + hh];
        float e = (qv.x + qv.y) + (qv.z + qv.w) + hdv;
        e = e > 0.f ? e : 0.2f * e;
        dd += __expf(e - mm);
      }
#pragma unroll
      for (int msk = L / 2; msk; msk >>= 1) dd += __shfl_xor(dd, msk);
      if (j == 0) { m_s[hh] = mm; inv_s[hh] = 1.f / (dd + 1e-16f); }
    }
    for (int base = p0; base < p1; base += CH) {
      int cend = base + CH < p1 ? base + CH : p1;
      __syncthreads();
      if (crew) {
        float hdv = hd_s[hh];
        float mmv = m_s[hh], inv = inv_s[hh];
        for (int p = base + j; p < cend; p += L) {
          float4 qv = hs4[(size_t)csr_src[p] * H + hh];
          float e = (qv.x + qv.y) + (qv.z + qv.w) + hdv;
          e = e > 0.f ? e : 0.2f * e;
          lalpha[(p - base) * PH + hh] = __expf(e - mmv) * inv;
        }
      }
      for (int idx = t; idx < cend - base; idx += TPB) lsrc[idx] = csr_src[base + idx];
      __syncthreads();
      for (int p = base; p < cend; ++p) {
        int s0 = lsrc[p - base];
        float a0 = lalpha[(p - base) * PH + head];
        const u16* h0 = h + (size_t)s0 * HC + c0;
        if constexpr (VPT == 16) {
          u16x8 va = *(const u16x8*)h0, vb = *(const u16x8*)(h0 + 8);
#pragma unroll
          for (int v = 0; v < 8; v++) {
            acc[v] += a0 * b2f(va[v]);
            acc[8 + v] += a0 * b2f(vb[v]);
          }
        } else if constexpr (VPT == 8) {
          u16x8 v0 = *(const u16x8*)h0;
#pragma unroll
          for (int v = 0; v < 8; v++) acc[v] += a0 * b2f(v0[v]);
        } else if constexpr (VPT == 4) {
          u16x4 v0 = *(const u16x4*)h0;
#pragma unroll
          for (int v = 0; v < 4; v++) acc[v] += a0 * b2f(v0[v]);
        } else {
          acc[0] += a0 * b2f(h0[0]);
        }
      }
    }
  }

  float r[VPT];
#pragma unroll
  for (int v = 0; v < VPT; v++) {
    r[v] = acc[v] + ldf(bias, c0 + v, isbf);
    if (do_elu) r[v] = r[v] > 0.f ? r[v] : expm1f(r[v]);
  }
  if (outb) {
    if constexpr (VPT == 16) {
      u16x8 oa, ob;
#pragma unroll
      for (int v = 0; v < 8; v++) { oa[v] = f2b(r[v]); ob[v] = f2b(r[8 + v]); }
      *(u16x8*)(outb + (size_t)i * HC + c0) = oa;
      *(u16x8*)(outb + (size_t)i * HC + c0 + 8) = ob;
    } else if constexpr (VPT == 8) {
      u16x8 o;
#pragma unroll
      for (int v = 0; v < 8; v++) o[v] = f2b(r[v]);
      *(u16x8*)(outb + (size_t)i * HC + c0) = o;
    } else if constexpr (VPT == 4) {
      u16x4 o;
#pragma unroll
      for (int v = 0; v < 4; v++) o[v] = f2b(r[v]);
      *(u16x4*)(outb + (size_t)i * HC + c0) = o;
    } else {
      outb[(size_t)i * HC + c0] = f2b(r[0]);
    }
  }
  if (outv) {
#pragma unroll
    for (int v = 0; v < VPT; v++)
      stf(outv, (size_t)10000 + (size_t)i * HC + c0 + v, isbf, r[v]);
  }
}

// ---------------------------------------------------------------- scores finish
__global__ void scores_kernel(const float* __restrict__ sc, const void* __restrict__ r3b,
                              void* __restrict__ scores, const int* __restrict__ FLAG) {
  int isbf = *FLAG;
  int i = blockIdx.x * 256 + threadIdx.x;
  if (i >= NN) return;
  float4 q = ((const float4*)sc)[i];
  stf(scores, i, isbf, (q.x + q.y) + (q.z + q.w) + ldf(r3b, 0, isbf));
}

// ---------------------------------------------------------------- launch
extern "C" void kernel_launch(void* const* d_in, const int* in_sizes, int n_in,
                              void* d_out, int out_size, void* d_ws, size_t ws_size,
                              hipStream_t stream) {
  const void* x   = d_in[0];
  const int* ei   = (const int*)d_in[1];
  const void* W1  = d_in[2];
  const void* as1 = d_in[3];
  const void* ad1 = d_in[4];
  const void* b1  = d_in[5];
  const void* W2  = d_in[6];
  const void* as2 = d_in[7];
  const void* ad2 = d_in[8];
  const void* b2  = d_in[9];
  const void* W3  = d_in[10];
  const void* as3 = d_in[11];
  const void* ad3 = d_in[12];
  const void* b3  = d_in[13];
  const void* r1w = d_in[14];
  const void* r1b = d_in[15];
  const void* r2w = d_in[16];
  const void* r2b = d_in[17];
  const void* r3w = d_in[18];
  const void* r3b = d_in[19];

  char* ws = (char*)d_ws;
  size_t o = 0;
  auto alloc = [&](size_t bytes) { void* p = ws + o; o += (bytes + 255) & ~(size_t)255; return p; };
  u16* XC     = (u16*)alloc((size_t)NN * 768 * 2);
  u16* W1T    = (u16*)alloc((size_t)2048 * 768 * 2);
  u16* W2T    = (u16*)alloc((size_t)1024 * 2048 * 2);
  u16* W3T    = (u16*)alloc((size_t)64 * 1024 * 2);
  u16* R1T    = (u16*)alloc((size_t)256 * 64 * 2);
  u16* R2T    = (u16*)alloc((size_t)128 * 256 * 2);
  u16* Hbuf   = (u16*)alloc((size_t)NN * 2048 * 2);
  u16* Xbuf   = (u16*)alloc((size_t)NN * 2048 * 2);
  u16* X3B    = (u16*)alloc((size_t)NN * 64 * 2);
  u16* H1B    = (u16*)alloc((size_t)NN * 256 * 2);
  // partial-sum layout: [node][head][4] floats per array
  float* HZ   = (float*)alloc((size_t)NN * 112 * 4);
  float* HS1  = HZ;                        // NN*8*4
  float* HD1  = HZ + (size_t)NN * 32;      // NN*8*4
  float* HS2  = HZ + (size_t)NN * 64;      // NN*4*4
  float* HD2  = HZ + (size_t)NN * 80;      // NN*4*4
  float* HS3  = HZ + (size_t)NN * 96;      // NN*1*4
  float* HD3  = HZ + (size_t)NN * 100;     // NN*1*4
  float* SC   = HZ + (size_t)NN * 104;     // NN*4 score partials
  float* SD   = HZ + (size_t)NN * 108;     // NN*4 dummy
  int* DEG    = (int*)alloc((size_t)NN * 4);
  int* OFFS   = (int*)alloc((size_t)(NN + 1) * 4);
  int* CURSOR = (int*)alloc((size_t)NN * 4);
  int* CSR    = (int*)alloc((size_t)NTOT * 4);
  int* FLAG   = (int*)alloc(256);

  cvt_kernel<<<(NN * 768 + 255) / 256, 256, 0, stream>>>(x, XC, NN * 768, FLAG);

  // batched weight transposes
  TD5 td;
  td.d[0] = {W1,  W1T, 768, 2048, 0};
  td.d[1] = {W2,  W2T, 2048, 1024, 0};
  td.d[2] = {W3,  W3T, 1024, 64, 0};
  td.d[3] = {r1w, R1T, 64, 256, 0};
  td.d[4] = {r2w, R2T, 256, 128, 0};
  int cum = 0;
  for (int k = 0; k < 5; k++) {
    td.d[k].t0 = cum;
    cum += (td.d[k].R / 32) * (td.d[k].C / 32);
  }
  transpose_all<<<cum, dim3(32, 8), 0, stream>>>(td, FLAG);

  init_kernel<<<(NN * 112 + 255) / 256, 256, 0, stream>>>(DEG, HZ, NN * 112);
  count_deg_kernel<<<(NE + 255) / 256, 256, 0, stream>>>(ei, DEG);
  scan_kernel<<<1, 1024, 0, stream>>>(DEG, OFFS, CURSOR, NN);
  scatter_kernel<<<(NTOT + 255) / 256, 256, 0, stream>>>(ei, CURSOR, CSR);

  const int MT = (NN + 127) / 128;   // 79
  const int MT64 = (NN + 63) / 64;   // 157

  // ---- layer 1: 768 -> 8 x 256
  gemm_kernel<64, 128, 2, 2><<<MT64 * 16, 256, 0, stream>>>(
      XC, W1T, Hbuf, NN, 768, 2048, 16, nullptr, 0, as1, ad1, HS1, HD1, 8, 256, FLAG);
  agg_fused_kernel<2048, 16, 128, 8, 96><<<NN, 128, 0, stream>>>(
      Hbuf, HS1, HD1, CSR, OFFS, b1, Xbuf, nullptr, 1, FLAG);

  // ---- layer 2: 2048 -> 4 x 256
  gemm_kernel<64, 128, 2, 2><<<MT64 * 8, 256, 0, stream>>>(
      Xbuf, W2T, Hbuf, NN, 2048, 1024, 8, nullptr, 0, as2, ad2, HS2, HD2, 4, 256, FLAG);
  agg_fused_kernel<1024, 8, 128, 4, 96><<<NN, 128, 0, stream>>>(
      Hbuf, HS2, HD2, CSR, OFFS, b2, Xbuf, nullptr, 1, FLAG);

  // ---- layer 3: 1024 -> 1 x 64
  gemm_kernel<128, 64, 4, 1><<<MT, 256, 0, stream>>>(
      Xbuf, W3T, Hbuf, NN, 1024, 64, 1, nullptr, 0, as3, ad3, HS3, HD3, 1, 64, FLAG);
  agg_fused_kernel<64, 1, 64, 1, 96><<<NN, 64, 0, stream>>>(
      Hbuf, HS3, HD3, CSR, OFFS, b3, X3B, d_out, 0, FLAG);

  // ---- reasoning MLP as MFMA GEMMs; final dot fused into 2nd GEMM epilogue
  gemm_kernel<64, 64, 2, 2><<<MT64 * 4, 256, 0, stream>>>(
      X3B, R1T, H1B, NN, 64, 256, 4, r1b, 1, nullptr, nullptr, nullptr, nullptr, 0, 0, FLAG);
  gemm_kernel<64, 64, 2, 2><<<MT64 * 2, 256, 0, stream>>>(
      H1B, R2T, nullptr, NN, 256, 128, 2, r2b, 1, r3w, r3w, SC, SD, 1, 128, FLAG);
  scores_kernel<<<(NN + 255) / 256, 256, 0, stream>>>(SC, r3b, d_out, FLAG);
}